// Round 4
// baseline (167.342 us; speedup 1.0000x reference)
//
#include <hip/hip_runtime.h>

typedef unsigned short u16;
typedef unsigned int   u32;

typedef __attribute__((ext_vector_type(4)))  float  f32x4;
typedef __attribute__((ext_vector_type(16))) float  f32x16;
typedef __attribute__((ext_vector_type(4)))  u32    u32x4;
typedef __attribute__((ext_vector_type(8)))  __bf16 bf16x8;

#define B_  2
#define L_  2048
#define H_  16

// ---------- bf16 helpers ----------
__device__ static inline u16 f2bf(float f) {
  u32 u = __builtin_bit_cast(u32, f);
  u32 r = u + 0x7fffu + ((u >> 16) & 1u);
  return (u16)(r >> 16);
}
__device__ static inline u32 pack2(float a, float b) {   // RTNE pair pack
  return (u32)f2bf(a) | ((u32)f2bf(b) << 16);
}
// one-instruction truncating pair pack: dst = {hi16(b), hi16(a)} via v_perm_b32
__device__ static inline u32 pack2t(float a, float b) {
  return __builtin_amdgcn_perm(__builtin_bit_cast(u32, b),
                               __builtin_bit_cast(u32, a), 0x07060302u);
}

// permlane32_swap: a' = {a.lo32lanes, b.lo32lanes}, b' = {a.hi32lanes, b.hi32lanes}
__device__ static inline void swap32p(u32& a, u32& b) {
  auto r = __builtin_amdgcn_permlane32_swap(a, b, false, false);
  a = r[0]; b = r[1];
}

// async global->LDS, 16B/lane. LDS dest = wave-uniform base + lane*16.
__device__ static inline void gload_lds16(const u16* g, u16* lds) {
  __builtin_amdgcn_global_load_lds((__attribute__((address_space(1))) void*)(g),
                                   (__attribute__((address_space(3))) void*)(lds),
                                   16, 0, 0);
}

// ---------------------------------------------------------------------------
// fused fp32 -> bf16 pack for x, Wqkv, Wo (RTNE — GEMM inputs keep accuracy).
// softmax 1/sqrt(dk)=0.125 folded into W_q rows (power-of-2: bit-identical P).
// ---------------------------------------------------------------------------
__global__ __launch_bounds__(256) void cvt3_kernel(
    const float4* __restrict__ a, uint2* __restrict__ ao, int na,
    const float4* __restrict__ b, uint2* __restrict__ bo, int nb,
    const float4* __restrict__ c, uint2* __restrict__ co, int nc)
{
  const int step = gridDim.x * 256;
  constexpr int nq = 1024 * 1024 / 4;          // float4 count of the W_q rows
  for (int i = blockIdx.x * 256 + threadIdx.x; i < na; i += step) {
    float4 f = a[i];
    ao[i] = make_uint2(pack2(f.x, f.y), pack2(f.z, f.w));
  }
  for (int i = blockIdx.x * 256 + threadIdx.x; i < nb; i += step) {
    float4 f = b[i];
    const float s = (i < nq) ? 0.125f : 1.0f;
    bo[i] = make_uint2(pack2(f.x * s, f.y * s), pack2(f.z * s, f.w * s));
  }
  for (int i = blockIdx.x * 256 + threadIdx.x; i < nc; i += step) {
    float4 f = c[i];
    co[i] = make_uint2(pack2(f.x, f.y), pack2(f.z, f.w));
  }
}

// ---------------------------------------------------------------------------
// GEMM (small-N / O-proj): C[M,N] = A[M,K] @ Bt[N,K]^T, m97 structure + R6
// swizzle. Kept for GEMM2 (N=1024) where 256^2 tiles would under-fill the grid.
// ---------------------------------------------------------------------------
template <bool OUT_F32, int NT, bool DBUF>
__global__ __launch_bounds__(256) void gemm_bt_kernel(
    const u16* __restrict__ A, const u16* __restrict__ Bt, void* __restrict__ Cv,
    const int K, const int N)
{
  constexpr int NB = DBUF ? 2 : 1;
  constexpr int JT = NT / 32;                    // j-tiles per wave
  __shared__ __attribute__((aligned(16))) u16 Al[NB][128 * 64];
  __shared__ __attribute__((aligned(16))) u16 Bl[NB][NT * 64];

  const int tid  = threadIdx.x;
  const int w    = tid >> 6;
  const int lane = tid & 63;
  const int m0 = blockIdx.y * 128;
  const int n0 = blockIdx.x * NT;
  const int mo = (w >> 1) * 64;
  const int no = (w & 1) * (NT / 2);

  const int sr8  = lane >> 3;                    // staging row-in-group
  const int scol = (((lane & 7) ^ ((lane >> 3) & 7)) * 8);   // swizzled source chunk

  const f32x4 zero = {0.f, 0.f, 0.f, 0.f};
  f32x4 acc[4][JT];
  #pragma unroll
  for (int i = 0; i < 4; ++i)
    #pragma unroll
    for (int j = 0; j < JT; ++j) acc[i][j] = zero;

  const int frow = lane & 15;
  const int fg   = lane >> 4;

  auto stage = [&](int buf, int k0) {
    #pragma unroll
    for (int inst = 0; inst < 4; ++inst) {
      const int r = w * 32 + inst * 8 + sr8;
      gload_lds16(A + (size_t)(m0 + r) * K + k0 + scol, &Al[buf][(w * 32 + inst * 8) * 64]);
    }
    #pragma unroll
    for (int inst = 0; inst < NT / 32; ++inst) {
      const int r = w * (NT / 4) + inst * 8 + sr8;
      gload_lds16(Bt + (size_t)(n0 + r) * K + k0 + scol, &Bl[buf][(w * (NT / 4) + inst * 8) * 64]);
    }
  };

  if (DBUF) stage(0, 0);

  int cur = 0;
  for (int k0 = 0; k0 < K; k0 += 64) {
    __syncthreads();
    if (DBUF) {
      if (k0 + 64 < K) stage(cur ^ 1, k0 + 64);
    } else {
      stage(0, k0);
      __syncthreads();
    }
    #pragma unroll
    for (int ks = 0; ks < 2; ++ks) {
      const int fco = ((ks * 4 + fg) ^ (frow & 7)) * 8;      // swizzled read chunk
      bf16x8 af[4], bfr[JT];
      #pragma unroll
      for (int i = 0; i < 4; ++i)
        af[i] = *(const bf16x8*)&Al[cur][(mo + i * 16 + frow) * 64 + fco];
      #pragma unroll
      for (int j = 0; j < JT; ++j)
        bfr[j] = *(const bf16x8*)&Bl[cur][(no + j * 16 + frow) * 64 + fco];
      #pragma unroll
      for (int i = 0; i < 4; ++i)
        #pragma unroll
        for (int j = 0; j < JT; ++j)
          acc[i][j] = __builtin_amdgcn_mfma_f32_16x16x32_bf16(af[i], bfr[j], acc[i][j], 0, 0, 0);
    }
    if (DBUF) cur ^= 1;
  }

  const int crow0 = m0 + mo + (lane >> 4) * 4;
  const int ccol0 = n0 + no + (lane & 15);
  #pragma unroll
  for (int i = 0; i < 4; ++i)
    #pragma unroll
    for (int j = 0; j < JT; ++j)
      #pragma unroll
      for (int r = 0; r < 4; ++r) {
        const size_t idx = (size_t)(crow0 + i * 16 + r) * N + (ccol0 + j * 16);
        if (OUT_F32) ((float*)Cv)[idx] = acc[i][j][r];
        else         ((u16*)Cv)[idx]   = f2bf(acc[i][j][r]);
      }
}

// ---------------------------------------------------------------------------
// GEMM1 (qkv-proj) — R13: 256x256 8-phase counted-vmcnt kernel (m201 port).
// 512 thr = 8 waves (2 wm x 4 wn), wave tile 128x64, BK=64, LDS 128 KiB
// (2 K-tile buffers), 1 block/CU, grid 192.
// Stage ledger (half-tile = 2 global_load_lds/wave):
//   tile s halves: A0 @ (s-2).P3 (post-MFMA), A1/B0/B1 @ (s-1).P0/P1/P2
//   single wait per K-tile: issue A0(t+2) then vmcnt(2) at t.P3 -> tile
//   t+1's 8 loads retire, A0(t+2) stays in flight. Raw s_barrier (no
//   compiler vmcnt-0 drain); lgkmcnt(0)+sched_barrier(0) per rule #18;
//   setprio(1) around each 16-MFMA quadrant (T5). Chunk-XOR swizzle (T2)
//   identical to the proven m97 kernel.
// ---------------------------------------------------------------------------
__global__ __launch_bounds__(512, 2) void gemm256_kernel(
    const u16* __restrict__ A, const u16* __restrict__ Bt, u16* __restrict__ C,
    const int K, const int N)
{
  __shared__ __attribute__((aligned(16))) u16 Al[2][256 * 64];
  __shared__ __attribute__((aligned(16))) u16 Bl[2][256 * 64];

  const int tid  = threadIdx.x;
  const int w    = tid >> 6;
  const int lane = tid & 63;
  const int wm   = w >> 2;                      // 0/1  -> row block of 128
  const int wn   = w & 3;                       // 0..3 -> col block of 64
  const int frow = lane & 15;
  const int fg   = lane >> 4;
  const int sr8  = lane >> 3;
  const int scol = (((lane & 7) ^ ((lane >> 3) & 7)) * 8);

  // XCD-bijective block swizzle (nwg = 192, 192 % 8 == 0)
  const int nbx = N >> 8;
  int id = blockIdx.y * gridDim.x + blockIdx.x;
  const int cpx = (gridDim.x * gridDim.y) >> 3;
  id = (id & 7) * cpx + (id >> 3);
  const int m0 = (id / nbx) * 256;
  const int n0 = (id % nbx) * 256;

  f32x4 acc[8][4];
  #pragma unroll
  for (int i = 0; i < 8; ++i)
    #pragma unroll
    for (int j = 0; j < 4; ++j) acc[i][j] = (f32x4){0.f, 0.f, 0.f, 0.f};

  // stage one 128-row half (2 insts/wave; 8 waves cover 128 rows)
  auto stageA = [&](int buf, int h, int k0) {
    #pragma unroll
    for (int j = 0; j < 2; ++j) {
      const int rbase = h * 128 + w * 16 + j * 8;
      gload_lds16(A + (size_t)(m0 + rbase + sr8) * K + k0 + scol, &Al[buf][rbase * 64]);
    }
  };
  auto stageB = [&](int buf, int h, int k0) {
    #pragma unroll
    for (int j = 0; j < 2; ++j) {
      const int rbase = h * 128 + w * 16 + j * 8;
      gload_lds16(Bt + (size_t)(n0 + rbase + sr8) * K + k0 + scol, &Bl[buf][rbase * 64]);
    }
  };

// one phase: ds-read quadrant frags; optional stage; barrier; lgkm0; 16 MFMA
#define PHASE(CBUF, Q, STAGE_STMT)                                              \
  {                                                                             \
    constexpr int mq = (Q) >> 1, nq = (Q) & 1;                                  \
    bf16x8 af[2][4];                                                            \
    bf16x8 bfr[2][2];                                                           \
    _Pragma("unroll")                                                           \
    for (int ks = 0; ks < 2; ++ks) {                                            \
      const int fco = ((ks * 4 + fg) ^ (frow & 7)) * 8;                         \
      _Pragma("unroll")                                                         \
      for (int i = 0; i < 4; ++i)                                               \
        af[ks][i] = *(const bf16x8*)&Al[CBUF][(wm * 128 + mq * 64 + i * 16 + frow) * 64 + fco]; \
      _Pragma("unroll")                                                         \
      for (int j = 0; j < 2; ++j)                                               \
        bfr[ks][j] = *(const bf16x8*)&Bl[CBUF][(wn * 64 + nq * 32 + j * 16 + frow) * 64 + fco]; \
    }                                                                           \
    STAGE_STMT;                                                                 \
    __builtin_amdgcn_s_barrier();                                               \
    asm volatile("s_waitcnt lgkmcnt(0)" ::: "memory");                          \
    __builtin_amdgcn_sched_barrier(0);                                          \
    __builtin_amdgcn_s_setprio(1);                                              \
    _Pragma("unroll")                                                           \
    for (int ks = 0; ks < 2; ++ks)                                              \
      _Pragma("unroll")                                                         \
      for (int i = 0; i < 4; ++i)                                               \
        _Pragma("unroll")                                                       \
        for (int j = 0; j < 2; ++j)                                             \
          acc[mq * 4 + i][nq * 2 + j] = __builtin_amdgcn_mfma_f32_16x16x32_bf16(\
              af[ks][i], bfr[ks][j], acc[mq * 4 + i][nq * 2 + j], 0, 0, 0);     \
    __builtin_amdgcn_s_setprio(0);                                              \
  }

  const int KT = K >> 6;                        // 64-wide K-tiles

  // prologue: tile 0 fully + A0 of tile 1 in flight
  stageA(0, 0, 0); stageA(0, 1, 0);
  stageB(0, 0, 0); stageB(0, 1, 0);
  if (KT > 1) {
    stageA(1, 0, 64);
    asm volatile("s_waitcnt vmcnt(2)" ::: "memory");
  } else {
    asm volatile("s_waitcnt vmcnt(0)" ::: "memory");
  }
  __builtin_amdgcn_s_barrier();

  for (int t = 0; t < KT; ++t) {
    const int  c  = t & 1;
    const bool h1 = (t + 1) < KT;
    const int  kn = (t + 1) << 6;

    PHASE(c, 0, if (h1) stageA(c ^ 1, 1, kn));
    __builtin_amdgcn_s_barrier();
    PHASE(c, 1, if (h1) stageB(c ^ 1, 0, kn));
    __builtin_amdgcn_s_barrier();
    PHASE(c, 2, if (h1) stageB(c ^ 1, 1, kn));
    __builtin_amdgcn_s_barrier();
    PHASE(c, 3, );
    if (t + 2 < KT) {
      stageA(c, 0, (t + 2) << 6);
      asm volatile("s_waitcnt vmcnt(2)" ::: "memory");
    } else {
      asm volatile("s_waitcnt vmcnt(0)" ::: "memory");
    }
    __builtin_amdgcn_s_barrier();
  }
#undef PHASE

  const int crow0 = m0 + wm * 128 + fg * 4;
  const int ccol0 = n0 + wn * 64 + frow;
  #pragma unroll
  for (int i = 0; i < 8; ++i)
    #pragma unroll
    for (int j = 0; j < 4; ++j)
      #pragma unroll
      for (int r = 0; r < 4; ++r)
        C[(size_t)(crow0 + i * 16 + r) * N + (ccol0 + j * 16)] = f2bf(acc[i][j][r]);
}

// ---------------------------------------------------------------------------
// MFMA causal flash attention — R12 structure (unchanged this round).
// 32x32 MFMA, 256 thr, 4 waves (qh x kh), 4 blocks/CU, P in-register via
// permlane32_swap, k-half combine via LDS overlay.
// ---------------------------------------------------------------------------
__global__ __launch_bounds__(256, 4) void attn_mfma_kernel(const u16* __restrict__ qkv,
                                                           u16* __restrict__ y)
{
  __shared__ __attribute__((aligned(16))) unsigned char smem[32768];

  const int tid  = threadIdx.x;
  const int w    = tid >> 6;                   // wave 0..3
  const int lane = tid & 63;
  const int ql   = lane & 31;                  // q-col (also d-row / k-row index)
  const int hi   = lane >> 5;
  const int qh   = w >> 1;                     // q-half of the 64-q tile
  const int kh   = w & 1;                      // k-half split
  const int bh   = blockIdx.x;                 // bh on x => XCD affinity
  const int bb   = bh >> 4;
  const int hh   = bh & 15;
  const size_t rb = (size_t)bb * L_;

  // load-balance remap: blocks at id, id+256, id+512, id+768 (same CU under
  // round-robin dispatch) get qt = {a, 31-a, 8+a, 23-a} -> 66 tiles total.
  const int a  = blockIdx.y & 7;
  const int cc = blockIdx.y >> 3;
  const int qt = (cc == 0) ? a : (cc == 1) ? (31 - a) : (cc == 2) ? (8 + a) : (23 - a);

  u16* Kt   = (u16*)(smem);                    // [buf*4096 + row*64 + col] bf16
  u32* Vtd  = (u32*)(smem + 16384);            // [buf*2048 + d*32 + kp] u32
  float* Ocmb = (float*)smem;                  // combine overlay [16][256] f32
  float* Lcmb = (float*)(smem + 16384);        // combine overlay [64] f32

  // V staging: thread handles key-pair column kkp, d-rows dc*8 .. dc*8+7
  const int kkp = lane & 31;
  const int dc  = 2 * w + (lane >> 5);         // 0..7

  // K staging (R6 swizzle): wave w stages rows w*16 .. w*16+15
  const int ksr = w * 16 + (lane >> 3);
  const int ksc = (((lane & 7) ^ ((lane >> 3) & 7)) * 8);

  const int q0 = qt * 64;
  const int qb = q0 + qh * 32;                 // wave's q-base; lane's q = qb+ql
  const int n  = qt + 1;                       // k-tiles for this tile

  // Q B-frags (32x32x16): qf[s] = Q[qb+ql][d = 16s + 8hi .. +7], W_q pre-scaled
  bf16x8 qf[4];
  #pragma unroll
  for (int s = 0; s < 4; ++s)
    qf[s] = *(const bf16x8*)(qkv + (rb + qb + ql) * 3072 + hh * 64 + s * 16 + 8 * hi);

  f32x16 oacc0 = {}, oacc1 = {};               // O^T d-tiles 0/1 (64 d x 32 q)
  float lsum = 0.f;

  auto stageK = [&](int buf, int kt) {
    #pragma unroll
    for (int inst = 0; inst < 2; ++inst)
      gload_lds16(qkv + (rb + kt + ksr + inst * 8) * 3072 + 1024 + hh * 64 + ksc,
                  &Kt[buf * 4096 + (w * 16 + inst * 8) * 64]);
  };
  auto loadV = [&](int kt, uint4& va, uint4& vb) {
    const u16* vp = qkv + (rb + kt + 2 * kkp) * 3072 + 2048 + hh * 64 + dc * 8;
    va = *(const uint4*)vp;
    vb = *(const uint4*)(vp + 3072);
  };
  auto writeV = [&](int buf, uint4 va, uint4 vb) {
    u16 a16[8], b16[8];
    *(uint4*)a16 = va; *(uint4*)b16 = vb;
    #pragma unroll
    for (int i = 0; i < 8; ++i)
      Vtd[buf * 2048 + (dc * 8 + i) * 32 + 4 * ((kkp >> 2) ^ i) + (kkp & 3)] =
          (u32)a16[i] | ((u32)b16[i] << 16);
  };

  // ---- prologue: stage tile 0 into buffer 0 ----
  {
    stageK(0, 0);
    uint4 va, vb;
    loadV(0, va, vb);
    writeV(0, va, vb);
  }

  int cur = 0;
  for (int it = 0; it < n; ++it) {
    __syncthreads();   // publishes K/V[cur]

    const int  kt       = it * 64;
    const bool havenext = (it + 1) < n;
    uint4 va, vb;
    if (havenext) {
      stageK(cur ^ 1, kt + 64);
      loadV(kt + 64, va, vb);
    }

    const bool diag = (kt == q0);
    if (!(diag && kh > qh)) {                  // (qh=0,kh=1) diag tile: all masked
      // S^T = K Q^T over this wave's k-half: 32q x 32k, chained over d (4x16)
      f32x16 sacc = {};
      __builtin_amdgcn_s_setprio(1);
      #pragma unroll
      for (int s = 0; s < 4; ++s) {
        bf16x8 kf = *(const bf16x8*)&Kt[cur * 4096 + (kh * 32 + ql) * 64 +
                                        (((2 * s + hi) ^ (ql & 7)) * 8)];
        sacc = __builtin_amdgcn_mfma_f32_32x32x16_bf16(kf, qf[s], sacc, 0, 0, 0);
      }
      __builtin_amdgcn_s_setprio(0);

      // p = exp(s); triangular mask only when kh==qh on the diag tile.
      // k-row(reg r) = (r&3) + 8*(r>>2) + 4*hi; pack pairs (rows 2j,2j+1).
      u32 u[8];
      if (diag && kh == qh) {
        #pragma unroll
        for (int j = 0; j < 8; ++j) {
          const int r0  = 2 * j;
          const int k0r = (r0 & 3) + 8 * (r0 >> 2) + 4 * hi;
          const float p0 = (k0r     > ql) ? 0.f : __expf(sacc[r0]);
          const float p1 = (k0r + 1 > ql) ? 0.f : __expf(sacc[r0 + 1]);
          lsum += p0 + p1;
          u[j] = pack2t(p0, p1);
        }
      } else {
        #pragma unroll
        for (int j = 0; j < 8; ++j) {
          const float p0 = __expf(sacc[2 * j]);
          const float p1 = __expf(sacc[2 * j + 1]);
          lsum += p0 + p1;
          u[j] = pack2t(p0, p1);
        }
      }

      // P^T B-frags in-register: swap k-row pair-groups across lane halves.
      swap32p(u[0], u[2]); swap32p(u[1], u[3]);      // ks=0: k-rows 8hi+0..7
      swap32p(u[4], u[6]); swap32p(u[5], u[7]);      // ks=1
      const bf16x8 pf0 = __builtin_bit_cast(bf16x8, (u32x4){u[0], u[1], u[2], u[3]});
      const bf16x8 pf1 = __builtin_bit_cast(bf16x8, (u32x4){u[4], u[5], u[6], u[7]});

      // O^T += V^T P^T (A = V^T[d 32-rows x 16 k], per d-tile, per 16-k step)
      __builtin_amdgcn_s_setprio(1);
      #pragma unroll
      for (int dt = 0; dt < 2; ++dt) {
        f32x16& oa = dt ? oacc1 : oacc0;
        const int d = dt * 32 + ql;
        bf16x8 vf0 = *(const bf16x8*)&Vtd[cur * 2048 + d * 32 + 4 * ((4 * kh + hi) ^ (ql & 7))];
        oa = __builtin_amdgcn_mfma_f32_32x32x16_bf16(vf0, pf0, oa, 0, 0, 0);
        bf16x8 vf1 = *(const bf16x8*)&Vtd[cur * 2048 + d * 32 + 4 * ((4 * kh + 2 + hi) ^ (ql & 7))];
        oa = __builtin_amdgcn_mfma_f32_32x32x16_bf16(vf1, pf1, oa, 0, 0, 0);
      }
      __builtin_amdgcn_s_setprio(0);
    }

    if (havenext) writeV(cur ^ 1, va, vb);
    cur ^= 1;
  }

  // l: combine the two hi-halves (each covers half the wave's k-rows)
  lsum += __shfl_xor(lsum, 32);

  // ---- combine the two k-half waves' partials (O = O0 + O1, l = l0 + l1) ----
  __syncthreads();   // all K/V LDS use done before overlaying combine area
  if (kh == 1) {
    #pragma unroll
    for (int dt = 0; dt < 2; ++dt)
      #pragma unroll
      for (int rq = 0; rq < 4; ++rq) {
        const f32x16& oa = dt ? oacc1 : oacc0;
        *(f32x4*)&Ocmb[(qh * 8 + dt * 4 + rq) * 256 + lane * 4] =
            (f32x4){oa[4 * rq], oa[4 * rq + 1], oa[4 * rq + 2], oa[4 * rq + 3]};
      }
    if (hi == 0) Lcmb[qh * 32 + ql] = lsum;
  }
  __syncthreads();
  if (kh == 0) {
    const float inv = 1.f / (lsum + Lcmb[qh * 32 + ql]);
    u16* yp = y + (rb + qb + ql) * 1024 + hh * 64;
    #pragma unroll
    for (int dt = 0; dt < 2; ++dt)
      #pragma unroll
      for (int rq = 0; rq < 4; ++rq) {
        const f32x16& oa = dt ? oacc1 : oacc0;
        const f32x4 oc = *(const f32x4*)&Ocmb[(qh * 8 + dt * 4 + rq) * 256 + lane * 4];
        const float v0 = (oa[4 * rq]     + oc[0]) * inv;
        const float v1 = (oa[4 * rq + 1] + oc[1]) * inv;
        const float v2 = (oa[4 * rq + 2] + oc[2]) * inv;
        const float v3 = (oa[4 * rq + 3] + oc[3]) * inv;
        // d = dt*32 + 8*rq + 4*hi + {0..3}
        *(uint2*)(yp + dt * 32 + 8 * rq + 4 * hi) = make_uint2(pack2(v0, v1), pack2(v2, v3));
      }
  }
}

// ---------------------------------------------------------------------------
extern "C" void kernel_launch(void* const* d_in, const int* in_sizes, int n_in,
                              void* d_out, int out_size, void* d_ws, size_t ws_size,
                              hipStream_t stream)
{
  const float* x    = (const float*)d_in[0];   // [B*L, 1024] fp32
  const float* Wqkv = (const float*)d_in[1];   // [3072, 1024] fp32
  const float* Wo   = (const float*)d_in[2];   // [1024, 1024] fp32
  float* out = (float*)d_out;                  // [B*L, 1024] fp32

  u16* xb    = (u16*)d_ws;                      // [4096,1024]  8 MiB
  u16* Wqkvb = xb    + (size_t)4096 * 1024;     // [3072,1024]  6 MiB
  u16* Wob   = Wqkvb + (size_t)3072 * 1024;     // [1024,1024]  2 MiB
  u16* qkv   = Wob   + (size_t)1024 * 1024;     // [4096,3072] 24 MiB
  u16* y     = qkv   + (size_t)4096 * 3072;     // [4096,1024]  8 MiB

  cvt3_kernel<<<dim3(2048), dim3(256), 0, stream>>>(
      (const float4*)x,    (uint2*)xb,    4096 * 1024 / 4,
      (const float4*)Wqkv, (uint2*)Wqkvb, 3072 * 1024 / 4,
      (const float4*)Wo,   (uint2*)Wob,   1024 * 1024 / 4);

  // qkv = x @ Wqkv^T   (M=4096, N=3072, K=1024)  [R13: 256^2 8-phase]
  gemm256_kernel<<<dim3(3072 / 256, 4096 / 256), dim3(512), 0, stream>>>(
      xb, Wqkvb, qkv, 1024, 3072);
  // causal MHA -> y [4096, 1024] bf16  (R12: 32x32 MFMA, 256 thr, 4 blk/CU)
  attn_mfma_kernel<<<dim3(B_ * H_, 32), dim3(256), 0, stream>>>(qkv, y);
  // out = y @ Wo^T     (M=4096, N=1024, K=1024), fp32 out
  gemm_bt_kernel<true, 64, true><<<dim3(1024 / 64, 4096 / 128), dim3(256), 0, stream>>>(
      y, Wob, out, 1024, 1024);
}

// Round 5
// 162.662 us; speedup vs baseline: 1.0288x; 1.0288x over previous
//
#include <hip/hip_runtime.h>

typedef unsigned short u16;
typedef unsigned int   u32;

typedef __attribute__((ext_vector_type(4)))  float  f32x4;
typedef __attribute__((ext_vector_type(16))) float  f32x16;
typedef __attribute__((ext_vector_type(4)))  u32    u32x4;
typedef __attribute__((ext_vector_type(8)))  __bf16 bf16x8;

#define B_  2
#define L_  2048
#define H_  16

// ---------- bf16 helpers ----------
__device__ static inline u16 f2bf(float f) {
  u32 u = __builtin_bit_cast(u32, f);
  u32 r = u + 0x7fffu + ((u >> 16) & 1u);
  return (u16)(r >> 16);
}
__device__ static inline u32 pack2(float a, float b) {   // RTNE pair pack
  return (u32)f2bf(a) | ((u32)f2bf(b) << 16);
}
// one-instruction truncating pair pack: dst = {hi16(b), hi16(a)} via v_perm_b32
__device__ static inline u32 pack2t(float a, float b) {
  return __builtin_amdgcn_perm(__builtin_bit_cast(u32, b),
                               __builtin_bit_cast(u32, a), 0x07060302u);
}

// permlane32_swap: a' = {a.lo32lanes, b.lo32lanes}, b' = {a.hi32lanes, b.hi32lanes}
__device__ static inline void swap32p(u32& a, u32& b) {
  auto r = __builtin_amdgcn_permlane32_swap(a, b, false, false);
  a = r[0]; b = r[1];
}

// async global->LDS, 16B/lane. LDS dest = wave-uniform base + lane*16.
__device__ static inline void gload_lds16(const u16* g, u16* lds) {
  __builtin_amdgcn_global_load_lds((__attribute__((address_space(1))) void*)(g),
                                   (__attribute__((address_space(3))) void*)(lds),
                                   16, 0, 0);
}

// ---------------------------------------------------------------------------
// fused fp32 -> bf16 pack for x, Wqkv, Wo (RTNE — GEMM inputs keep accuracy).
// softmax 1/sqrt(dk)=0.125 folded into W_q rows (power-of-2: bit-identical P).
// ---------------------------------------------------------------------------
__global__ __launch_bounds__(256) void cvt3_kernel(
    const float4* __restrict__ a, uint2* __restrict__ ao, int na,
    const float4* __restrict__ b, uint2* __restrict__ bo, int nb,
    const float4* __restrict__ c, uint2* __restrict__ co, int nc)
{
  const int step = gridDim.x * 256;
  constexpr int nq = 1024 * 1024 / 4;          // float4 count of the W_q rows
  for (int i = blockIdx.x * 256 + threadIdx.x; i < na; i += step) {
    float4 f = a[i];
    ao[i] = make_uint2(pack2(f.x, f.y), pack2(f.z, f.w));
  }
  for (int i = blockIdx.x * 256 + threadIdx.x; i < nb; i += step) {
    float4 f = b[i];
    const float s = (i < nq) ? 0.125f : 1.0f;
    bo[i] = make_uint2(pack2(f.x * s, f.y * s), pack2(f.z * s, f.w * s));
  }
  for (int i = blockIdx.x * 256 + threadIdx.x; i < nc; i += step) {
    float4 f = c[i];
    co[i] = make_uint2(pack2(f.x, f.y), pack2(f.z, f.w));
  }
}

// ---------------------------------------------------------------------------
// GEMM (small-N / O-proj): C[M,N] = A[M,K] @ Bt[N,K]^T, m97 structure + R6
// swizzle. Kept for GEMM2 (N=1024) where 256-wide tiles under-fill the grid.
// ---------------------------------------------------------------------------
template <bool OUT_F32, int NT, bool DBUF>
__global__ __launch_bounds__(256) void gemm_bt_kernel(
    const u16* __restrict__ A, const u16* __restrict__ Bt, void* __restrict__ Cv,
    const int K, const int N)
{
  constexpr int NB = DBUF ? 2 : 1;
  constexpr int JT = NT / 32;                    // j-tiles per wave
  __shared__ __attribute__((aligned(16))) u16 Al[NB][128 * 64];
  __shared__ __attribute__((aligned(16))) u16 Bl[NB][NT * 64];

  const int tid  = threadIdx.x;
  const int w    = tid >> 6;
  const int lane = tid & 63;
  const int m0 = blockIdx.y * 128;
  const int n0 = blockIdx.x * NT;
  const int mo = (w >> 1) * 64;
  const int no = (w & 1) * (NT / 2);

  const int sr8  = lane >> 3;                    // staging row-in-group
  const int scol = (((lane & 7) ^ ((lane >> 3) & 7)) * 8);   // swizzled source chunk

  const f32x4 zero = {0.f, 0.f, 0.f, 0.f};
  f32x4 acc[4][JT];
  #pragma unroll
  for (int i = 0; i < 4; ++i)
    #pragma unroll
    for (int j = 0; j < JT; ++j) acc[i][j] = zero;

  const int frow = lane & 15;
  const int fg   = lane >> 4;

  auto stage = [&](int buf, int k0) {
    #pragma unroll
    for (int inst = 0; inst < 4; ++inst) {
      const int r = w * 32 + inst * 8 + sr8;
      gload_lds16(A + (size_t)(m0 + r) * K + k0 + scol, &Al[buf][(w * 32 + inst * 8) * 64]);
    }
    #pragma unroll
    for (int inst = 0; inst < NT / 32; ++inst) {
      const int r = w * (NT / 4) + inst * 8 + sr8;
      gload_lds16(Bt + (size_t)(n0 + r) * K + k0 + scol, &Bl[buf][(w * (NT / 4) + inst * 8) * 64]);
    }
  };

  if (DBUF) stage(0, 0);

  int cur = 0;
  for (int k0 = 0; k0 < K; k0 += 64) {
    __syncthreads();
    if (DBUF) {
      if (k0 + 64 < K) stage(cur ^ 1, k0 + 64);
    } else {
      stage(0, k0);
      __syncthreads();
    }
    #pragma unroll
    for (int ks = 0; ks < 2; ++ks) {
      const int fco = ((ks * 4 + fg) ^ (frow & 7)) * 8;      // swizzled read chunk
      bf16x8 af[4], bfr[JT];
      #pragma unroll
      for (int i = 0; i < 4; ++i)
        af[i] = *(const bf16x8*)&Al[cur][(mo + i * 16 + frow) * 64 + fco];
      #pragma unroll
      for (int j = 0; j < JT; ++j)
        bfr[j] = *(const bf16x8*)&Bl[cur][(no + j * 16 + frow) * 64 + fco];
      #pragma unroll
      for (int i = 0; i < 4; ++i)
        #pragma unroll
        for (int j = 0; j < JT; ++j)
          acc[i][j] = __builtin_amdgcn_mfma_f32_16x16x32_bf16(af[i], bfr[j], acc[i][j], 0, 0, 0);
    }
    if (DBUF) cur ^= 1;
  }

  const int crow0 = m0 + mo + (lane >> 4) * 4;
  const int ccol0 = n0 + no + (lane & 15);
  #pragma unroll
  for (int i = 0; i < 4; ++i)
    #pragma unroll
    for (int j = 0; j < JT; ++j)
      #pragma unroll
      for (int r = 0; r < 4; ++r) {
        const size_t idx = (size_t)(crow0 + i * 16 + r) * N + (ccol0 + j * 16);
        if (OUT_F32) ((float*)Cv)[idx] = acc[i][j][r];
        else         ((u16*)Cv)[idx]   = f2bf(acc[i][j][r]);
      }
}

// ---------------------------------------------------------------------------
// GEMM1 (qkv-proj) — R14: grid-fill + deep-flight fix of the R13 8-phase.
//   * BM=256, BN=192 -> grid 16x16 = 256 blocks = exactly 1/CU (R13's 192
//     blocks idled 25% of the machine).
//   * ALL 7 stage loads for tile t+1 issue at t.P0 (target buffer c^1 whose
//     reads completed before t-1's final barrier -> provably safe); single
//     vmcnt(0) after t.P3's MFMA -> ~3.5 phases (~1200cy) of flight vs R13's
//     1 phase. This was the 6600-cyc/K-tile stall.
//   * B-fragments ds_read once per K-tile (P0) and held in registers across
//     the 4 phases: 40 -> 22 b128 reads per wave per K-tile.
//   * Everything else identical: chunk-XOR swizzle (T2), raw s_barrier,
//     lgkmcnt(0)+sched_barrier(0) (rule #18), setprio (T5), XCD swizzle (T1).
// ---------------------------------------------------------------------------
__global__ __launch_bounds__(512, 2) void gemm256_kernel(
    const u16* __restrict__ A, const u16* __restrict__ Bt, u16* __restrict__ C,
    const int K, const int N)
{
  __shared__ __attribute__((aligned(16))) u16 Al[2][256 * 64];
  __shared__ __attribute__((aligned(16))) u16 Bl[2][192 * 64];

  const int tid  = threadIdx.x;
  const int w    = tid >> 6;
  const int lane = tid & 63;
  const int wm   = w >> 2;                      // 0/1  -> row block of 128
  const int wn   = w & 3;                       // 0..3 -> col block of 48
  const int frow = lane & 15;
  const int fg   = lane >> 4;
  const int sr8  = lane >> 3;
  const int scol = (((lane & 7) ^ ((lane >> 3) & 7)) * 8);

  // XCD-bijective block swizzle (nwg = 256, 256 % 8 == 0)
  const int nbx = N / 192;                      // 16
  int id = blockIdx.y * gridDim.x + blockIdx.x;
  const int cpx = (gridDim.x * gridDim.y) >> 3;
  id = (id & 7) * cpx + (id >> 3);
  const int m0 = (id / nbx) * 256;
  const int n0 = (id % nbx) * 192;

  f32x4 acc[8][3];
  #pragma unroll
  for (int i = 0; i < 8; ++i)
    #pragma unroll
    for (int j = 0; j < 3; ++j) acc[i][j] = (f32x4){0.f, 0.f, 0.f, 0.f};

  // full K-tile stage: A 256 rows (4 insts/wave), B 192 rows (3 insts/wave)
  auto stageAll = [&](int buf, int k0) {
    #pragma unroll
    for (int j = 0; j < 4; ++j) {
      const int rbase = w * 32 + j * 8;
      gload_lds16(A + (size_t)(m0 + rbase + sr8) * K + k0 + scol, &Al[buf][rbase * 64]);
    }
    #pragma unroll
    for (int j = 0; j < 3; ++j) {
      const int rbase = w * 24 + j * 8;
      gload_lds16(Bt + (size_t)(n0 + rbase + sr8) * K + k0 + scol, &Bl[buf][rbase * 64]);
    }
  };

// one phase: ds-read 4 A-frags (i = 2Q,2Q+1); EXTRA (bfr load / stage);
// barrier; lgkm0; sched_barrier; 12 MFMA under setprio.
#define DO_PHASE(Q, EXTRA)                                                      \
  {                                                                             \
    bf16x8 af[2][2];                                                            \
    _Pragma("unroll")                                                           \
    for (int ks = 0; ks < 2; ++ks) {                                            \
      const int fco = ((ks * 4 + fg) ^ (frow & 7)) * 8;                         \
      _Pragma("unroll")                                                         \
      for (int i = 0; i < 2; ++i)                                               \
        af[ks][i] = *(const bf16x8*)&Al[c][(wm * 128 + ((Q) * 2 + i) * 16 + frow) * 64 + fco]; \
    }                                                                           \
    EXTRA;                                                                      \
    __builtin_amdgcn_s_barrier();                                               \
    asm volatile("s_waitcnt lgkmcnt(0)" ::: "memory");                          \
    __builtin_amdgcn_sched_barrier(0);                                          \
    __builtin_amdgcn_s_setprio(1);                                              \
    _Pragma("unroll")                                                           \
    for (int ks = 0; ks < 2; ++ks)                                              \
      _Pragma("unroll")                                                         \
      for (int i = 0; i < 2; ++i)                                               \
        _Pragma("unroll")                                                       \
        for (int j = 0; j < 3; ++j)                                             \
          acc[(Q) * 2 + i][j] = __builtin_amdgcn_mfma_f32_16x16x32_bf16(        \
              af[ks][i], bfr[ks][j], acc[(Q) * 2 + i][j], 0, 0, 0);             \
    __builtin_amdgcn_s_setprio(0);                                              \
  }

  const int KT = K >> 6;                        // 64-wide K-tiles

  // prologue: tile 0 staged, full drain (one unavoidable latency hit)
  stageAll(0, 0);
  asm volatile("s_waitcnt vmcnt(0)" ::: "memory");
  __builtin_amdgcn_s_barrier();

  for (int t = 0; t < KT; ++t) {
    const int  c  = t & 1;
    const bool h1 = (t + 1) < KT;
    const int  kn = (t + 1) << 6;
    bf16x8 bfr[2][3];                           // B-frags persist across phases

    DO_PHASE(0, {
      _Pragma("unroll")
      for (int ks = 0; ks < 2; ++ks) {
        const int fco = ((ks * 4 + fg) ^ (frow & 7)) * 8;
        _Pragma("unroll")
        for (int j = 0; j < 3; ++j)
          bfr[ks][j] = *(const bf16x8*)&Bl[c][(wn * 48 + j * 16 + frow) * 64 + fco];
      }
      if (h1) stageAll(c ^ 1, kn);              // ALL of tile t+1, 3.5 phases early
    });
    __builtin_amdgcn_s_barrier();
    DO_PHASE(1, );
    __builtin_amdgcn_s_barrier();
    DO_PHASE(2, );
    __builtin_amdgcn_s_barrier();
    DO_PHASE(3, );
    asm volatile("s_waitcnt vmcnt(0)" ::: "memory");   // t+1's 7 loads retire
    __builtin_amdgcn_s_barrier();
  }
#undef DO_PHASE

  const int crow0 = m0 + wm * 128 + fg * 4;
  const int ccol0 = n0 + wn * 48 + frow;
  #pragma unroll
  for (int i = 0; i < 8; ++i)
    #pragma unroll
    for (int j = 0; j < 3; ++j)
      #pragma unroll
      for (int r = 0; r < 4; ++r)
        C[(size_t)(crow0 + i * 16 + r) * N + (ccol0 + j * 16)] = f2bf(acc[i][j][r]);
}

// ---------------------------------------------------------------------------
// MFMA causal flash attention — R12 structure (unchanged this round).
// 32x32 MFMA, 256 thr, 4 waves (qh x kh), 4 blocks/CU, P in-register via
// permlane32_swap, k-half combine via LDS overlay.
// ---------------------------------------------------------------------------
__global__ __launch_bounds__(256, 4) void attn_mfma_kernel(const u16* __restrict__ qkv,
                                                           u16* __restrict__ y)
{
  __shared__ __attribute__((aligned(16))) unsigned char smem[32768];

  const int tid  = threadIdx.x;
  const int w    = tid >> 6;                   // wave 0..3
  const int lane = tid & 63;
  const int ql   = lane & 31;                  // q-col (also d-row / k-row index)
  const int hi   = lane >> 5;
  const int qh   = w >> 1;                     // q-half of the 64-q tile
  const int kh   = w & 1;                      // k-half split
  const int bh   = blockIdx.x;                 // bh on x => XCD affinity
  const int bb   = bh >> 4;
  const int hh   = bh & 15;
  const size_t rb = (size_t)bb * L_;

  // load-balance remap: blocks at id, id+256, id+512, id+768 (same CU under
  // round-robin dispatch) get qt = {a, 31-a, 8+a, 23-a} -> 66 tiles total.
  const int a  = blockIdx.y & 7;
  const int cc = blockIdx.y >> 3;
  const int qt = (cc == 0) ? a : (cc == 1) ? (31 - a) : (cc == 2) ? (8 + a) : (23 - a);

  u16* Kt   = (u16*)(smem);                    // [buf*4096 + row*64 + col] bf16
  u32* Vtd  = (u32*)(smem + 16384);            // [buf*2048 + d*32 + kp] u32
  float* Ocmb = (float*)smem;                  // combine overlay [16][256] f32
  float* Lcmb = (float*)(smem + 16384);        // combine overlay [64] f32

  // V staging: thread handles key-pair column kkp, d-rows dc*8 .. dc*8+7
  const int kkp = lane & 31;
  const int dc  = 2 * w + (lane >> 5);         // 0..7

  // K staging (R6 swizzle): wave w stages rows w*16 .. w*16+15
  const int ksr = w * 16 + (lane >> 3);
  const int ksc = (((lane & 7) ^ ((lane >> 3) & 7)) * 8);

  const int q0 = qt * 64;
  const int qb = q0 + qh * 32;                 // wave's q-base; lane's q = qb+ql
  const int n  = qt + 1;                       // k-tiles for this tile

  // Q B-frags (32x32x16): qf[s] = Q[qb+ql][d = 16s + 8hi .. +7], W_q pre-scaled
  bf16x8 qf[4];
  #pragma unroll
  for (int s = 0; s < 4; ++s)
    qf[s] = *(const bf16x8*)(qkv + (rb + qb + ql) * 3072 + hh * 64 + s * 16 + 8 * hi);

  f32x16 oacc0 = {}, oacc1 = {};               // O^T d-tiles 0/1 (64 d x 32 q)
  float lsum = 0.f;

  auto stageK = [&](int buf, int kt) {
    #pragma unroll
    for (int inst = 0; inst < 2; ++inst)
      gload_lds16(qkv + (rb + kt + ksr + inst * 8) * 3072 + 1024 + hh * 64 + ksc,
                  &Kt[buf * 4096 + (w * 16 + inst * 8) * 64]);
  };
  auto loadV = [&](int kt, uint4& va, uint4& vb) {
    const u16* vp = qkv + (rb + kt + 2 * kkp) * 3072 + 2048 + hh * 64 + dc * 8;
    va = *(const uint4*)vp;
    vb = *(const uint4*)(vp + 3072);
  };
  auto writeV = [&](int buf, uint4 va, uint4 vb) {
    u16 a16[8], b16[8];
    *(uint4*)a16 = va; *(uint4*)b16 = vb;
    #pragma unroll
    for (int i = 0; i < 8; ++i)
      Vtd[buf * 2048 + (dc * 8 + i) * 32 + 4 * ((kkp >> 2) ^ i) + (kkp & 3)] =
          (u32)a16[i] | ((u32)b16[i] << 16);
  };

  // ---- prologue: stage tile 0 into buffer 0 ----
  {
    stageK(0, 0);
    uint4 va, vb;
    loadV(0, va, vb);
    writeV(0, va, vb);
  }

  int cur = 0;
  for (int it = 0; it < n; ++it) {
    __syncthreads();   // publishes K/V[cur]

    const int  kt       = it * 64;
    const bool havenext = (it + 1) < n;
    uint4 va, vb;
    if (havenext) {
      stageK(cur ^ 1, kt + 64);
      loadV(kt + 64, va, vb);
    }

    const bool diag = (kt == q0);
    if (!(diag && kh > qh)) {                  // (qh=0,kh=1) diag tile: all masked
      // S^T = K Q^T over this wave's k-half: 32q x 32k, chained over d (4x16)
      f32x16 sacc = {};
      __builtin_amdgcn_s_setprio(1);
      #pragma unroll
      for (int s = 0; s < 4; ++s) {
        bf16x8 kf = *(const bf16x8*)&Kt[cur * 4096 + (kh * 32 + ql) * 64 +
                                        (((2 * s + hi) ^ (ql & 7)) * 8)];
        sacc = __builtin_amdgcn_mfma_f32_32x32x16_bf16(kf, qf[s], sacc, 0, 0, 0);
      }
      __builtin_amdgcn_s_setprio(0);

      // p = exp(s); triangular mask only when kh==qh on the diag tile.
      // k-row(reg r) = (r&3) + 8*(r>>2) + 4*hi; pack pairs (rows 2j,2j+1).
      u32 u[8];
      if (diag && kh == qh) {
        #pragma unroll
        for (int j = 0; j < 8; ++j) {
          const int r0  = 2 * j;
          const int k0r = (r0 & 3) + 8 * (r0 >> 2) + 4 * hi;
          const float p0 = (k0r     > ql) ? 0.f : __expf(sacc[r0]);
          const float p1 = (k0r + 1 > ql) ? 0.f : __expf(sacc[r0 + 1]);
          lsum += p0 + p1;
          u[j] = pack2t(p0, p1);
        }
      } else {
        #pragma unroll
        for (int j = 0; j < 8; ++j) {
          const float p0 = __expf(sacc[2 * j]);
          const float p1 = __expf(sacc[2 * j + 1]);
          lsum += p0 + p1;
          u[j] = pack2t(p0, p1);
        }
      }

      // P^T B-frags in-register: swap k-row pair-groups across lane halves.
      swap32p(u[0], u[2]); swap32p(u[1], u[3]);      // ks=0: k-rows 8hi+0..7
      swap32p(u[4], u[6]); swap32p(u[5], u[7]);      // ks=1
      const bf16x8 pf0 = __builtin_bit_cast(bf16x8, (u32x4){u[0], u[1], u[2], u[3]});
      const bf16x8 pf1 = __builtin_bit_cast(bf16x8, (u32x4){u[4], u[5], u[6], u[7]});

      // O^T += V^T P^T (A = V^T[d 32-rows x 16 k], per d-tile, per 16-k step)
      __builtin_amdgcn_s_setprio(1);
      #pragma unroll
      for (int dt = 0; dt < 2; ++dt) {
        f32x16& oa = dt ? oacc1 : oacc0;
        const int d = dt * 32 + ql;
        bf16x8 vf0 = *(const bf16x8*)&Vtd[cur * 2048 + d * 32 + 4 * ((4 * kh + hi) ^ (ql & 7))];
        oa = __builtin_amdgcn_mfma_f32_32x32x16_bf16(vf0, pf0, oa, 0, 0, 0);
        bf16x8 vf1 = *(const bf16x8*)&Vtd[cur * 2048 + d * 32 + 4 * ((4 * kh + 2 + hi) ^ (ql & 7))];
        oa = __builtin_amdgcn_mfma_f32_32x32x16_bf16(vf1, pf1, oa, 0, 0, 0);
      }
      __builtin_amdgcn_s_setprio(0);
    }

    if (havenext) writeV(cur ^ 1, va, vb);
    cur ^= 1;
  }

  // l: combine the two hi-halves (each covers half the wave's k-rows)
  lsum += __shfl_xor(lsum, 32);

  // ---- combine the two k-half waves' partials (O = O0 + O1, l = l0 + l1) ----
  __syncthreads();   // all K/V LDS use done before overlaying combine area
  if (kh == 1) {
    #pragma unroll
    for (int dt = 0; dt < 2; ++dt)
      #pragma unroll
      for (int rq = 0; rq < 4; ++rq) {
        const f32x16& oa = dt ? oacc1 : oacc0;
        *(f32x4*)&Ocmb[(qh * 8 + dt * 4 + rq) * 256 + lane * 4] =
            (f32x4){oa[4 * rq], oa[4 * rq + 1], oa[4 * rq + 2], oa[4 * rq + 3]};
      }
    if (hi == 0) Lcmb[qh * 32 + ql] = lsum;
  }
  __syncthreads();
  if (kh == 0) {
    const float inv = 1.f / (lsum + Lcmb[qh * 32 + ql]);
    u16* yp = y + (rb + qb + ql) * 1024 + hh * 64;
    #pragma unroll
    for (int dt = 0; dt < 2; ++dt)
      #pragma unroll
      for (int rq = 0; rq < 4; ++rq) {
        const f32x16& oa = dt ? oacc1 : oacc0;
        const f32x4 oc = *(const f32x4*)&Ocmb[(qh * 8 + dt * 4 + rq) * 256 + lane * 4];
        const float v0 = (oa[4 * rq]     + oc[0]) * inv;
        const float v1 = (oa[4 * rq + 1] + oc[1]) * inv;
        const float v2 = (oa[4 * rq + 2] + oc[2]) * inv;
        const float v3 = (oa[4 * rq + 3] + oc[3]) * inv;
        // d = dt*32 + 8*rq + 4*hi + {0..3}
        *(uint2*)(yp + dt * 32 + 8 * rq + 4 * hi) = make_uint2(pack2(v0, v1), pack2(v2, v3));
      }
  }
}

// ---------------------------------------------------------------------------
extern "C" void kernel_launch(void* const* d_in, const int* in_sizes, int n_in,
                              void* d_out, int out_size, void* d_ws, size_t ws_size,
                              hipStream_t stream)
{
  const float* x    = (const float*)d_in[0];   // [B*L, 1024] fp32
  const float* Wqkv = (const float*)d_in[1];   // [3072, 1024] fp32
  const float* Wo   = (const float*)d_in[2];   // [1024, 1024] fp32
  float* out = (float*)d_out;                  // [B*L, 1024] fp32

  u16* xb    = (u16*)d_ws;                      // [4096,1024]  8 MiB
  u16* Wqkvb = xb    + (size_t)4096 * 1024;     // [3072,1024]  6 MiB
  u16* Wob   = Wqkvb + (size_t)3072 * 1024;     // [1024,1024]  2 MiB
  u16* qkv   = Wob   + (size_t)1024 * 1024;     // [4096,3072] 24 MiB
  u16* y     = qkv   + (size_t)4096 * 3072;     // [4096,1024]  8 MiB

  cvt3_kernel<<<dim3(2048), dim3(256), 0, stream>>>(
      (const float4*)x,    (uint2*)xb,    4096 * 1024 / 4,
      (const float4*)Wqkv, (uint2*)Wqkvb, 3072 * 1024 / 4,
      (const float4*)Wo,   (uint2*)Wob,   1024 * 1024 / 4);

  // qkv = x @ Wqkv^T   (M=4096, N=3072, K=1024)  [R14: 256x192, 256 blocks]
  gemm256_kernel<<<dim3(3072 / 192, 4096 / 256), dim3(512), 0, stream>>>(
      xb, Wqkvb, qkv, 1024, 3072);
  // causal MHA -> y [4096, 1024] bf16  (R12: 32x32 MFMA, 256 thr, 4 blk/CU)
  attn_mfma_kernel<<<dim3(B_ * H_, 32), dim3(256), 0, stream>>>(qkv, y);
  // out = y @ Wo^T     (M=4096, N=1024, K=1024), fp32 out
  gemm_bt_kernel<true, 64, true><<<dim3(1024 / 64, 4096 / 128), dim3(256), 0, stream>>>(
      y, Wob, out, 1024, 1024);
}